// Round 8
// baseline (1324.095 us; speedup 1.0000x reference)
//
#include <hip/hip_runtime.h>
#include <hip/hip_bf16.h>
#include <cstdint>

#define B_ 2
#define T_ 2048
#define D_ 512
#define H_ 8
#define DK_ 64
#define TQ_ 4
#define NT_ (T_ / TQ_)   // 512 tiles of 4 rows
#define M_ (B_ * T_)     // 4096

// ---------------- GEMM: C[M,N] = A[M,K] @ W[K,N] + bias[N] ----------------
__global__ __launch_bounds__(256) void gemm_bias_kernel(
    const float* __restrict__ A, const float* __restrict__ W,
    const float* __restrict__ bias, float* __restrict__ C,
    int M, int N, int K)
{
  __shared__ float As[16][68];  // transposed A tile: As[k][m]
  __shared__ float Bs[16][68];
  const int bm = blockIdx.y * 64;
  const int bn = blockIdx.x * 64;
  const int tid = threadIdx.x;
  const int tx = tid & 15, ty = tid >> 4;
  float acc[4][4] = {};
  for (int k0 = 0; k0 < K; k0 += 16) {
    {
      const int r = tid >> 2;           // 0..63
      const int c = (tid & 3) << 2;     // 0,4,8,12
      const float4 a = *reinterpret_cast<const float4*>(&A[(size_t)(bm + r) * K + k0 + c]);
      As[c + 0][r] = a.x; As[c + 1][r] = a.y; As[c + 2][r] = a.z; As[c + 3][r] = a.w;
    }
    {
      const int r = tid >> 4;           // 0..15
      const int c = (tid & 15) << 2;    // 0..60
      *reinterpret_cast<float4*>(&Bs[r][c]) =
          *reinterpret_cast<const float4*>(&W[(size_t)(k0 + r) * N + bn + c]);
    }
    __syncthreads();
#pragma unroll
    for (int kk = 0; kk < 16; ++kk) {
      float av[4], bv[4];
#pragma unroll
      for (int i = 0; i < 4; ++i) av[i] = As[kk][ty * 4 + i];
#pragma unroll
      for (int j = 0; j < 4; ++j) bv[j] = Bs[kk][tx * 4 + j];
#pragma unroll
      for (int i = 0; i < 4; ++i)
#pragma unroll
        for (int j = 0; j < 4; ++j) acc[i][j] += av[i] * bv[j];
    }
    __syncthreads();
  }
#pragma unroll
  for (int i = 0; i < 4; ++i) {
    const int row = bm + ty * 4 + i;
#pragma unroll
    for (int j = 0; j < 4; ++j) {
      const int col = bn + tx * 4 + j;
      C[(size_t)row * N + col] = acc[i][j] + bias[col];
    }
  }
}

// Same GEMM but writes C TRANSPOSED: Ct[N][M].
__global__ __launch_bounds__(256) void gemm_bias_kernelT(
    const float* __restrict__ A, const float* __restrict__ W,
    const float* __restrict__ bias, float* __restrict__ Ct,
    int M, int N, int K)
{
  __shared__ float As[16][68];
  __shared__ float Bs[16][68];
  const int bm = blockIdx.y * 64;
  const int bn = blockIdx.x * 64;
  const int tid = threadIdx.x;
  const int tx = tid & 15, ty = tid >> 4;
  float acc[4][4] = {};
  for (int k0 = 0; k0 < K; k0 += 16) {
    {
      const int r = tid >> 2;
      const int c = (tid & 3) << 2;
      const float4 a = *reinterpret_cast<const float4*>(&A[(size_t)(bm + r) * K + k0 + c]);
      As[c + 0][r] = a.x; As[c + 1][r] = a.y; As[c + 2][r] = a.z; As[c + 3][r] = a.w;
    }
    {
      const int r = tid >> 4;
      const int c = (tid & 15) << 2;
      *reinterpret_cast<float4*>(&Bs[r][c]) =
          *reinterpret_cast<const float4*>(&W[(size_t)(k0 + r) * N + bn + c]);
    }
    __syncthreads();
#pragma unroll
    for (int kk = 0; kk < 16; ++kk) {
      float av[4], bv[4];
#pragma unroll
      for (int i = 0; i < 4; ++i) av[i] = As[kk][ty * 4 + i];
#pragma unroll
      for (int j = 0; j < 4; ++j) bv[j] = Bs[kk][tx * 4 + j];
#pragma unroll
      for (int i = 0; i < 4; ++i)
#pragma unroll
        for (int j = 0; j < 4; ++j) acc[i][j] += av[i] * bv[j];
    }
    __syncthreads();
  }
#pragma unroll
  for (int j = 0; j < 4; ++j) {
    const int col = bn + tx * 4 + j;
    const float bb = bias[col];
    const float4 v = make_float4(acc[0][j] + bb, acc[1][j] + bb, acc[2][j] + bb, acc[3][j] + bb);
    *reinterpret_cast<float4*>(&Ct[(size_t)col * M + bm + ty * 4]) = v;
  }
}

// ---------------- V_combined = mean over heads of V ----------------
__global__ __launch_bounds__(256) void vcombine_kernel(const float* __restrict__ V,
                                                       float* __restrict__ Vc)
{
  const int idx = blockIdx.x * 256 + threadIdx.x;
  if (idx >= M_ * DK_) return;
  const int row = idx >> 6, d = idx & 63;
  float s = 0.f;
#pragma unroll
  for (int h = 0; h < H_; ++h) s += V[(size_t)row * D_ + h * DK_ + d];
  Vc[idx] = s * 0.125f;
}

// ---------------- fused causal scores + 1.5-entmax ----------------
// MODE 3: real kernel (identical to round-7 version).
// MODE 0: ABLATION — score phase only, x4 repeat per head (kept live via asm).
// MODE 1: ABLATION — score x1 + entmax phase x4 repeat per head.
// Diagnostics never write global memory.
template <int MODE>
__global__ __launch_bounds__(256, 4)
__attribute__((amdgpu_waves_per_eu(4, 4)))
void attn_ab(
    const float* __restrict__ Qg, const float* __restrict__ Kt,
    const float* __restrict__ Vc, float* __restrict__ wavg,
    float* __restrict__ attn_out)
{
  __shared__ float sc[TQ_][T_];        // 32 KB
  __shared__ float4 qs4[TQ_][16];      // 1 KB
  __shared__ float part[4][TQ_][DK_];  // 4 KB

  const int tid = threadIdx.x;
  const int b = blockIdx.x & 1;
  const int tile = (NT_ - 1) - (blockIdx.x >> 1);  // heavy tiles first
  const int t0 = tile * TQ_;
  const int nS = t0 + TQ_;
  const int wave = __builtin_amdgcn_readfirstlane(tid >> 6);
  const int lane = tid & 63;
  const int n = t0 + wave + 1;
  float* const scw = &sc[wave][0];

  float wacc[32];
#pragma unroll
  for (int j = 0; j < 32; ++j) wacc[j] = 0.f;

  for (int h = 0; h < H_; ++h) {
    __syncthreads();
    if (tid < TQ_ * 16) {
      const int r = tid >> 4, d4 = tid & 15;
      qs4[r][d4] = *reinterpret_cast<const float4*>(
          &Qg[(size_t)(b * T_ + t0 + r) * D_ + h * DK_ + d4 * 4]);
    }
    __syncthreads();

    const int SREP = (MODE == 0) ? 4 : 1;
#pragma unroll 1
    for (int rep = 0; rep < SREP; ++rep) {
      // scores: z[r][s] = (Q[t0+r] . K[s]) * 0.0625, s < nS.
      for (int s0 = tid * 4; s0 < nS; s0 += 1024) {
        const float* Ktp = &Kt[(size_t)(h * DK_) * M_ + b * T_ + s0];
        float4 acc0 = {}, acc1 = {}, acc2 = {}, acc3 = {};
#pragma unroll 2
        for (int d4 = 0; d4 < 16; ++d4) {
          const float4 q0 = qs4[0][d4];
          const float4 q1 = qs4[1][d4];
          const float4 q2 = qs4[2][d4];
          const float4 q3 = qs4[3][d4];
          const float4 k0 = *reinterpret_cast<const float4*>(Ktp + (size_t)(d4 * 4 + 0) * M_);
          const float4 k1 = *reinterpret_cast<const float4*>(Ktp + (size_t)(d4 * 4 + 1) * M_);
          const float4 k2 = *reinterpret_cast<const float4*>(Ktp + (size_t)(d4 * 4 + 2) * M_);
          const float4 k3 = *reinterpret_cast<const float4*>(Ktp + (size_t)(d4 * 4 + 3) * M_);
#define FMA4(a, qv, kv) a.x = fmaf(qv, kv.x, a.x); a.y = fmaf(qv, kv.y, a.y); \
                        a.z = fmaf(qv, kv.z, a.z); a.w = fmaf(qv, kv.w, a.w)
          FMA4(acc0, q0.x, k0); FMA4(acc0, q0.y, k1); FMA4(acc0, q0.z, k2); FMA4(acc0, q0.w, k3);
          FMA4(acc1, q1.x, k0); FMA4(acc1, q1.y, k1); FMA4(acc1, q1.z, k2); FMA4(acc1, q1.w, k3);
          FMA4(acc2, q2.x, k0); FMA4(acc2, q2.y, k1); FMA4(acc2, q2.z, k2); FMA4(acc2, q2.w, k3);
          FMA4(acc3, q3.x, k0); FMA4(acc3, q3.y, k1); FMA4(acc3, q3.z, k2); FMA4(acc3, q3.w, k3);
#undef FMA4
        }
        acc0.x *= 0.0625f; acc0.y *= 0.0625f; acc0.z *= 0.0625f; acc0.w *= 0.0625f;
        acc1.x *= 0.0625f; acc1.y *= 0.0625f; acc1.z *= 0.0625f; acc1.w *= 0.0625f;
        acc2.x *= 0.0625f; acc2.y *= 0.0625f; acc2.z *= 0.0625f; acc2.w *= 0.0625f;
        acc3.x *= 0.0625f; acc3.y *= 0.0625f; acc3.z *= 0.0625f; acc3.w *= 0.0625f;
        *reinterpret_cast<float4*>(&sc[0][s0]) = acc0;
        *reinterpret_cast<float4*>(&sc[1][s0]) = acc1;
        *reinterpret_cast<float4*>(&sc[2][s0]) = acc2;
        *reinterpret_cast<float4*>(&sc[3][s0]) = acc3;
      }
      if (MODE == 0) {
        // keep this rep's work live; "memory" stops folding of repeats
        float dv = sc[0][(tid * 4) & (T_ - 1)];
        asm volatile("" :: "v"(dv) : "memory");
      }
    }
    if (MODE == 0) continue;  // skip entmax entirely

    __syncthreads();

    const int NREP = (MODE == 1) ? 4 : 1;
#pragma unroll 1
    for (int rep = 0; rep < NREP; ++rep) {
      // staging sweep
      float srow[32];
#pragma unroll
      for (int j = 0; j < 32; ++j) {
        if (j * 64 < n) {
          const int s = lane + j * 64;
          const float v = scw[s];
          srow[j] = (s < n) ? v : -1e30f;
        }
      }
      asm volatile("" ::: "memory");

      // max reduce
      float mx = -1e30f;
#pragma unroll
      for (int j = 0; j < 32; ++j)
        if (j * 64 < n) mx = fmaxf(mx, srow[j]);
#pragma unroll
      for (int m = 32; m >= 1; m >>= 1) mx = fmaxf(mx, __shfl_xor(mx, m, 64));

      // Newton on f(tau) = sum max(z-tau,0)^2 - 1
      float tau = mx - 1.0f;
#pragma unroll 1
      for (int it = 0; it < 16; ++it) {
        float s1 = 0.f, s2 = 0.f;
#pragma unroll
        for (int j = 0; j < 32; ++j) {
          if (j * 64 < n) {
            const float u = fmaxf(srow[j] - tau, 0.f);
            s1 += u;
            s2 = fmaf(u, u, s2);
          }
        }
#pragma unroll
        for (int m = 32; m >= 1; m >>= 1) {
          s1 += __shfl_xor(s1, m, 64);
          s2 += __shfl_xor(s2, m, 64);
        }
        if (s2 - 1.0f < 1e-5f) break;
        tau += (s2 - 1.0f) / fmaxf(2.f * s1, 1e-12f);
      }
      tau = fminf(tau, mx - 1e-8f);

      // accumulate weights
#pragma unroll
      for (int j = 0; j < 32; ++j) {
        if (j * 64 < n) {
          const float u = fmaxf(srow[j] - tau, 0.f);
          wacc[j] = fmaf(u, u, wacc[j]);
        }
      }
      if (MODE == 1) asm volatile("" ::: "memory");
    }
  }

  if (MODE == 0) return;
  if (MODE == 1) {
#pragma unroll
    for (int j = 0; j < 32; ++j) asm volatile("" :: "v"(wacc[j]));
    return;
  }

  // ---- MODE 3 epilogue (real outputs) ----
  __syncthreads();
#pragma unroll
  for (int j = 0; j < 32; ++j) scw[lane + j * 64] = wacc[j];
  __syncthreads();

  for (int i4 = tid; i4 < TQ_ * T_ / 4; i4 += 256) {
    const int r = i4 >> 9;
    const int c4 = i4 & 511;
    float4 w = reinterpret_cast<const float4*>(&sc[r][0])[c4];
    w.x *= 0.125f; w.y *= 0.125f; w.z *= 0.125f; w.w *= 0.125f;
    reinterpret_cast<float4*>(&wavg[(size_t)(b * T_ + t0 + r) * T_])[c4] = w;
  }

  {
    const int sg = wave, dd = lane;
    float acc0 = 0.f, acc1 = 0.f, acc2 = 0.f, acc3 = 0.f;
    for (int s = sg; s < nS; s += 4) {
      const float v = Vc[(size_t)(b * T_ + s) * DK_ + dd];
      acc0 += sc[0][s] * v;
      acc1 += sc[1][s] * v;
      acc2 += sc[2][s] * v;
      acc3 += sc[3][s] * v;
    }
    part[sg][0][dd] = acc0;
    part[sg][1][dd] = acc1;
    part[sg][2][dd] = acc2;
    part[sg][3][dd] = acc3;
  }
  __syncthreads();
  {
    const int r = wave, dd = lane;
    const float o = (part[0][r][dd] + part[1][r][dd] + part[2][r][dd] + part[3][r][dd]) * 0.125f;
    attn_out[(size_t)(b * T_ + t0 + r) * DK_ + dd] = o;
  }
}

extern "C" void kernel_launch(void* const* d_in, const int* in_sizes, int n_in,
                              void* d_out, int out_size, void* d_ws, size_t ws_size,
                              hipStream_t stream)
{
  const float* x  = (const float*)d_in[0];
  const float* Wq = (const float*)d_in[1];
  const float* bq = (const float*)d_in[2];
  const float* Wk = (const float*)d_in[3];
  const float* bk = (const float*)d_in[4];
  const float* Wv = (const float*)d_in[5];
  const float* bv = (const float*)d_in[6];
  const float* Wo = (const float*)d_in[7];
  const float* bo = (const float*)d_in[8];
  float* out = (float*)d_out;
  float* ws  = (float*)d_ws;

  float* Q  = ws;                        // [M,512]
  float* Kt = Q + (size_t)M_ * D_;       // [512,M]
  float* V  = Kt + (size_t)D_ * M_;      // [M,512]
  float* Vc = V + (size_t)M_ * D_;       // [M,64]
  float* AO = Vc + (size_t)M_ * DK_;     // [M,64]

  float* out1 = out;                    // [B,T,D]
  float* wavg = out + (size_t)M_ * D_;  // [B,T,T]

  const dim3 gp(D_ / 64, M_ / 64);  // (8, 64)
  gemm_bias_kernel <<<gp, 256, 0, stream>>>(x, Wq, bq, Q,  M_, D_, D_);
  gemm_bias_kernelT<<<gp, 256, 0, stream>>>(x, Wk, bk, Kt, M_, D_, D_);
  gemm_bias_kernel <<<gp, 256, 0, stream>>>(x, Wv, bv, V,  M_, D_, D_);
  vcombine_kernel<<<(M_ * DK_ + 255) / 256, 256, 0, stream>>>(V, Vc);

  // ---- diagnostics (no global writes; read-only on Q/Kt/Vc) ----
  attn_ab<0><<<B_ * NT_, 256, 0, stream>>>(Q, Kt, Vc, wavg, AO);  // score x4
  attn_ab<1><<<B_ * NT_, 256, 0, stream>>>(Q, Kt, Vc, wavg, AO);  // score + entmax x4

  // ---- real ----
  attn_ab<3><<<B_ * NT_, 256, 0, stream>>>(Q, Kt, Vc, wavg, AO);
  gemm_bias_kernel<<<gp, 256, 0, stream>>>(AO, Wo, bo, out1, M_, D_, DK_);
}

// Round 9
// 402.389 us; speedup vs baseline: 3.2906x; 3.2906x over previous
//
#include <hip/hip_runtime.h>
#include <hip/hip_bf16.h>
#include <cstdint>

#define B_ 2
#define T_ 2048
#define D_ 512
#define H_ 8
#define DK_ 64
#define TQ_ 8                 // rows per block (= waves per block)
#define NTL_ (T_ / TQ_)       // 256 tiles
#define M_ (B_ * T_)          // 4096

// ---------------- GEMM: C[M,N] = A[M,K] @ W[K,N] + bias[N] ----------------
__global__ __launch_bounds__(256) void gemm_bias_kernel(
    const float* __restrict__ A, const float* __restrict__ W,
    const float* __restrict__ bias, float* __restrict__ C,
    int M, int N, int K)
{
  __shared__ float As[16][68];  // transposed A tile: As[k][m]
  __shared__ float Bs[16][68];
  const int bm = blockIdx.y * 64;
  const int bn = blockIdx.x * 64;
  const int tid = threadIdx.x;
  const int tx = tid & 15, ty = tid >> 4;
  float acc[4][4] = {};
  for (int k0 = 0; k0 < K; k0 += 16) {
    {
      const int r = tid >> 2;           // 0..63
      const int c = (tid & 3) << 2;     // 0,4,8,12
      const float4 a = *reinterpret_cast<const float4*>(&A[(size_t)(bm + r) * K + k0 + c]);
      As[c + 0][r] = a.x; As[c + 1][r] = a.y; As[c + 2][r] = a.z; As[c + 3][r] = a.w;
    }
    {
      const int r = tid >> 4;           // 0..15
      const int c = (tid & 15) << 2;    // 0..60
      *reinterpret_cast<float4*>(&Bs[r][c]) =
          *reinterpret_cast<const float4*>(&W[(size_t)(k0 + r) * N + bn + c]);
    }
    __syncthreads();
#pragma unroll
    for (int kk = 0; kk < 16; ++kk) {
      float av[4], bv[4];
#pragma unroll
      for (int i = 0; i < 4; ++i) av[i] = As[kk][ty * 4 + i];
#pragma unroll
      for (int j = 0; j < 4; ++j) bv[j] = Bs[kk][tx * 4 + j];
#pragma unroll
      for (int i = 0; i < 4; ++i)
#pragma unroll
        for (int j = 0; j < 4; ++j) acc[i][j] += av[i] * bv[j];
    }
    __syncthreads();
  }
#pragma unroll
  for (int i = 0; i < 4; ++i) {
    const int row = bm + ty * 4 + i;
#pragma unroll
    for (int j = 0; j < 4; ++j) {
      const int col = bn + tx * 4 + j;
      C[(size_t)row * N + col] = acc[i][j] + bias[col];
    }
  }
}

// Same GEMM but writes C TRANSPOSED: Ct[N][M].
__global__ __launch_bounds__(256) void gemm_bias_kernelT(
    const float* __restrict__ A, const float* __restrict__ W,
    const float* __restrict__ bias, float* __restrict__ Ct,
    int M, int N, int K)
{
  __shared__ float As[16][68];
  __shared__ float Bs[16][68];
  const int bm = blockIdx.y * 64;
  const int bn = blockIdx.x * 64;
  const int tid = threadIdx.x;
  const int tx = tid & 15, ty = tid >> 4;
  float acc[4][4] = {};
  for (int k0 = 0; k0 < K; k0 += 16) {
    {
      const int r = tid >> 2;
      const int c = (tid & 3) << 2;
      const float4 a = *reinterpret_cast<const float4*>(&A[(size_t)(bm + r) * K + k0 + c]);
      As[c + 0][r] = a.x; As[c + 1][r] = a.y; As[c + 2][r] = a.z; As[c + 3][r] = a.w;
    }
    {
      const int r = tid >> 4;
      const int c = (tid & 15) << 2;
      *reinterpret_cast<float4*>(&Bs[r][c]) =
          *reinterpret_cast<const float4*>(&W[(size_t)(k0 + r) * N + bn + c]);
    }
    __syncthreads();
#pragma unroll
    for (int kk = 0; kk < 16; ++kk) {
      float av[4], bv[4];
#pragma unroll
      for (int i = 0; i < 4; ++i) av[i] = As[kk][ty * 4 + i];
#pragma unroll
      for (int j = 0; j < 4; ++j) bv[j] = Bs[kk][tx * 4 + j];
#pragma unroll
      for (int i = 0; i < 4; ++i)
#pragma unroll
        for (int j = 0; j < 4; ++j) acc[i][j] += av[i] * bv[j];
    }
    __syncthreads();
  }
#pragma unroll
  for (int j = 0; j < 4; ++j) {
    const int col = bn + tx * 4 + j;
    const float bb = bias[col];
    const float4 v = make_float4(acc[0][j] + bb, acc[1][j] + bb, acc[2][j] + bb, acc[3][j] + bb);
    *reinterpret_cast<float4*>(&Ct[(size_t)col * M + bm + ty * 4]) = v;
  }
}

// ---------------- V_combined = mean over heads of V ----------------
__global__ __launch_bounds__(256) void vcombine_kernel(const float* __restrict__ V,
                                                       float* __restrict__ Vc)
{
  const int idx = blockIdx.x * 256 + threadIdx.x;
  if (idx >= M_ * DK_) return;
  const int row = idx >> 6, d = idx & 63;
  float s = 0.f;
#pragma unroll
  for (int h = 0; h < H_; ++h) s += V[(size_t)row * D_ + h * DK_ + d];
  Vc[idx] = s * 0.125f;
}

// ---------------- fused causal scores + 1.5-entmax (8 rows / 8 waves / block) ----------------
// Wave r owns row t0+r. Score phase: one pass, thread covers s = 4*tid..4*tid+3.
// Q for head h+1 is prefetched into qs4[(h+1)&1] overlapped with entmax(h).
// Entmax: 3 Michelot (exact tau on current support) jumps, then Newton; break |f|<1e-5.
__global__ __launch_bounds__(512, 4)
void attn_kernel(
    const float* __restrict__ Qg, const float* __restrict__ Kt,
    const float* __restrict__ Vc, float* __restrict__ wavg,
    float* __restrict__ attn_out)
{
  __shared__ float sc[TQ_][T_];         // 64 KB: scores; reused as wsum at end
  __shared__ float4 qs4[2][TQ_][16];    // 4 KB, double-buffered per head
  __shared__ float part[4][TQ_][DK_];   // 8 KB: PV partials

  const int tid = threadIdx.x;
  const int b = blockIdx.x & 1;
  const int tile = (NTL_ - 1) - (blockIdx.x >> 1);  // heavy tiles first
  const int t0 = tile * TQ_;
  const int nS = t0 + TQ_;              // needed s range [0, nS)
  const int wave = __builtin_amdgcn_readfirstlane(tid >> 6);  // 0..7
  const int lane = tid & 63;
  const int n = t0 + wave + 1;          // support size for this wave's row
  float* const scw = &sc[wave][0];

  float wacc[32];
#pragma unroll
  for (int j = 0; j < 32; ++j) wacc[j] = 0.f;

  // preload head-0 Q
  if (tid < TQ_ * 16) {
    const int r = tid >> 4, d4 = tid & 15;
    qs4[0][r][d4] = *reinterpret_cast<const float4*>(
        &Qg[(size_t)(b * T_ + t0 + r) * D_ + 0 * DK_ + d4 * 4]);
  }
  __syncthreads();

  for (int h = 0; h < H_; ++h) {
    // ---- scores: z[r][s] = (Q[t0+r].K[s]) * 0.0625, one pass over s ----
    const int s0 = tid * 4;
    if (s0 < nS) {
      const float* Ktp = &Kt[(size_t)(h * DK_) * M_ + b * T_ + s0];
      float4 a[TQ_];
#pragma unroll
      for (int r = 0; r < TQ_; ++r) a[r] = make_float4(0.f, 0.f, 0.f, 0.f);
#pragma unroll 2
      for (int d4 = 0; d4 < 16; ++d4) {
        const float4 k0 = *reinterpret_cast<const float4*>(Ktp + (size_t)(d4 * 4 + 0) * M_);
        const float4 k1 = *reinterpret_cast<const float4*>(Ktp + (size_t)(d4 * 4 + 1) * M_);
        const float4 k2 = *reinterpret_cast<const float4*>(Ktp + (size_t)(d4 * 4 + 2) * M_);
        const float4 k3 = *reinterpret_cast<const float4*>(Ktp + (size_t)(d4 * 4 + 3) * M_);
#pragma unroll
        for (int r = 0; r < TQ_; ++r) {
          const float4 q = qs4[h & 1][r][d4];  // LDS same-address broadcast
          a[r].x = fmaf(q.x, k0.x, a[r].x); a[r].y = fmaf(q.x, k0.y, a[r].y);
          a[r].z = fmaf(q.x, k0.z, a[r].z); a[r].w = fmaf(q.x, k0.w, a[r].w);
          a[r].x = fmaf(q.y, k1.x, a[r].x); a[r].y = fmaf(q.y, k1.y, a[r].y);
          a[r].z = fmaf(q.y, k1.z, a[r].z); a[r].w = fmaf(q.y, k1.w, a[r].w);
          a[r].x = fmaf(q.z, k2.x, a[r].x); a[r].y = fmaf(q.z, k2.y, a[r].y);
          a[r].z = fmaf(q.z, k2.z, a[r].z); a[r].w = fmaf(q.z, k2.w, a[r].w);
          a[r].x = fmaf(q.w, k3.x, a[r].x); a[r].y = fmaf(q.w, k3.y, a[r].y);
          a[r].z = fmaf(q.w, k3.z, a[r].z); a[r].w = fmaf(q.w, k3.w, a[r].w);
        }
      }
#pragma unroll
      for (int r = 0; r < TQ_; ++r) {
        a[r].x *= 0.0625f; a[r].y *= 0.0625f; a[r].z *= 0.0625f; a[r].w *= 0.0625f;
        *reinterpret_cast<float4*>(&sc[r][s0]) = a[r];
      }
    }
    __syncthreads();

    // prefetch next head's Q (overlaps with entmax below)
    if (h + 1 < H_ && tid < TQ_ * 16) {
      const int r = tid >> 4, d4 = tid & 15;
      qs4[(h + 1) & 1][r][d4] = *reinterpret_cast<const float4*>(
          &Qg[(size_t)(b * T_ + t0 + r) * D_ + (h + 1) * DK_ + d4 * 4]);
    }

    // ---- 1.5-entmax on row t0+wave ----
    float srow[32];
#pragma unroll
    for (int j = 0; j < 32; ++j) {
      if (j * 64 < n) {                   // scalar guard (n is SGPR)
        const int s = lane + j * 64;
        const float v = scw[s];
        srow[j] = (s < n) ? v : -1e30f;
      }
    }

    float mx = -1e30f;
#pragma unroll
    for (int j = 0; j < 32; ++j)
      if (j * 64 < n) mx = fmaxf(mx, srow[j]);
#pragma unroll
    for (int m = 32; m >= 1; m >>= 1) mx = fmaxf(mx, __shfl_xor(mx, m, 64));

    // tau0 = mx-1 (f >= 0). 3 Michelot jumps (exact tau for current support),
    // then Newton (globally convergent for convex decreasing f from either side).
    float tau = mx - 1.0f;
#pragma unroll 1
    for (int it = 0; it < 12; ++it) {
      float s1 = 0.f, s2 = 0.f, cn = 0.f;
#pragma unroll
      for (int j = 0; j < 32; ++j) {
        if (j * 64 < n) {
          const float u = fmaxf(srow[j] - tau, 0.f);
          s1 += u;
          s2 = fmaf(u, u, s2);
          cn += (u > 0.f) ? 1.f : 0.f;
        }
      }
#pragma unroll
      for (int m = 32; m >= 1; m >>= 1) {
        s1 += __shfl_xor(s1, m, 64);
        s2 += __shfl_xor(s2, m, 64);
      }
      if (fabsf(s2 - 1.0f) < 1e-5f) break;  // wave-uniform
      if (it < 3) {
#pragma unroll
        for (int m = 32; m >= 1; m >>= 1) cn += __shfl_xor(cn, m, 64);
        const float kf = fmaxf(cn, 1.f);
        const float mu = tau + s1 / kf;                  // mean of support
        const float ss = s2 - s1 * s1 / kf;              // k * variance
        tau = mu - sqrtf(fmaxf((1.0f - ss) / kf, 0.f));  // exact tau for this support
      } else {
        tau += (s2 - 1.0f) / fmaxf(2.f * s1, 1e-12f);    // Newton
      }
    }
    tau = fminf(tau, mx - 1e-8f);

#pragma unroll
    for (int j = 0; j < 32; ++j) {
      if (j * 64 < n) {
        const float u = fmaxf(srow[j] - tau, 0.f);
        wacc[j] = fmaf(u, u, wacc[j]);
      }
    }
    __syncthreads();  // entmax done; sc free for next head's scores; qs4 next visible
  }

  // dump register weights to LDS (full row; tails are zero)
#pragma unroll
  for (int j = 0; j < 32; ++j) scw[lane + j * 64] = wacc[j];
  __syncthreads();

  // weights_avg: coalesced float4 stores, full T rows
  for (int i4 = tid; i4 < TQ_ * T_ / 4; i4 += 512) {
    const int r = i4 >> 9;                 // / (T_/4 = 512)
    const int c4 = i4 & 511;
    float4 w = reinterpret_cast<const float4*>(&sc[r][0])[c4];
    w.x *= 0.125f; w.y *= 0.125f; w.z *= 0.125f; w.w *= 0.125f;
    reinterpret_cast<float4*>(&wavg[(size_t)(b * T_ + t0 + r) * T_])[c4] = w;
  }

  // PV: wave w handles s = (w&3) mod 4, rows (w>>2)*4 .. +3
  {
    const int sg = wave & 3;
    const int rb = (wave >> 2) * 4;
    float a0 = 0.f, a1 = 0.f, a2 = 0.f, a3 = 0.f;
    for (int s = sg; s < nS; s += 4) {
      const float v = Vc[(size_t)(b * T_ + s) * DK_ + lane];
      a0 += sc[rb + 0][s] * v;
      a1 += sc[rb + 1][s] * v;
      a2 += sc[rb + 2][s] * v;
      a3 += sc[rb + 3][s] * v;
    }
    part[sg][rb + 0][lane] = a0;
    part[sg][rb + 1][lane] = a1;
    part[sg][rb + 2][lane] = a2;
    part[sg][rb + 3][lane] = a3;
  }
  __syncthreads();
  {
    const int r = wave;
    const float o = (part[0][r][lane] + part[1][r][lane] +
                     part[2][r][lane] + part[3][r][lane]) * 0.125f;
    attn_out[(size_t)(b * T_ + t0 + r) * DK_ + lane] = o;
  }
}

extern "C" void kernel_launch(void* const* d_in, const int* in_sizes, int n_in,
                              void* d_out, int out_size, void* d_ws, size_t ws_size,
                              hipStream_t stream)
{
  const float* x  = (const float*)d_in[0];
  const float* Wq = (const float*)d_in[1];
  const float* bq = (const float*)d_in[2];
  const float* Wk = (const float*)d_in[3];
  const float* bk = (const float*)d_in[4];
  const float* Wv = (const float*)d_in[5];
  const float* bv = (const float*)d_in[6];
  const float* Wo = (const float*)d_in[7];
  const float* bo = (const float*)d_in[8];
  float* out = (float*)d_out;
  float* ws  = (float*)d_ws;

  float* Q  = ws;                        // [M,512]
  float* Kt = Q + (size_t)M_ * D_;       // [512,M]
  float* V  = Kt + (size_t)D_ * M_;      // [M,512]
  float* Vc = V + (size_t)M_ * D_;       // [M,64]
  float* AO = Vc + (size_t)M_ * DK_;     // [M,64]

  float* out1 = out;                    // [B,T,D]
  float* wavg = out + (size_t)M_ * D_;  // [B,T,T]

  const dim3 gp(D_ / 64, M_ / 64);  // (8, 64)
  gemm_bias_kernel <<<gp, 256, 0, stream>>>(x, Wq, bq, Q,  M_, D_, D_);
  gemm_bias_kernelT<<<gp, 256, 0, stream>>>(x, Wk, bk, Kt, M_, D_, D_);
  gemm_bias_kernel <<<gp, 256, 0, stream>>>(x, Wv, bv, V,  M_, D_, D_);
  vcombine_kernel<<<(M_ * DK_ + 255) / 256, 256, 0, stream>>>(V, Vc);
  attn_kernel<<<B_ * NTL_, 512, 0, stream>>>(Q, Kt, Vc, wavg, AO);
  gemm_bias_kernel<<<gp, 256, 0, stream>>>(AO, Wo, bo, out1, M_, D_, DK_);
}

// Round 10
// 376.444 us; speedup vs baseline: 3.5174x; 1.0689x over previous
//
#include <hip/hip_runtime.h>
#include <hip/hip_bf16.h>
#include <cstdint>

#define B_ 2
#define T_ 2048
#define D_ 512
#define H_ 8
#define DK_ 64
#define TQ_ 8                 // rows per block (= waves per block)
#define NTL_ (T_ / TQ_)       // 256 tiles
#define M_ (B_ * T_)          // 4096

// ---------------- GEMM: C[M,N] = A[M,K] @ W[K,N] + bias[N] ----------------
// 64x64 tile, BK=32, 256 threads, 4x4 per thread, float4 LDS reads in inner loop.
__global__ __launch_bounds__(256) void gemm_bias_kernel(
    const float* __restrict__ A, const float* __restrict__ W,
    const float* __restrict__ bias, float* __restrict__ C,
    int M, int N, int K)
{
  __shared__ float As[32][68];  // transposed A tile: As[k][m]
  __shared__ float Bs[32][68];
  const int bm = blockIdx.y * 64;
  const int bn = blockIdx.x * 64;
  const int tid = threadIdx.x;
  const int tx = tid & 15, ty = tid >> 4;
  float acc[4][4] = {};
  for (int k0 = 0; k0 < K; k0 += 32) {
    {
      const int r = tid >> 2;           // 0..63
      const int c = (tid & 3) << 2;     // 0,4,8,12
      const float4 a0 = *reinterpret_cast<const float4*>(&A[(size_t)(bm + r) * K + k0 + c]);
      const float4 a1 = *reinterpret_cast<const float4*>(&A[(size_t)(bm + r) * K + k0 + 16 + c]);
      As[c + 0][r] = a0.x;  As[c + 1][r] = a0.y;  As[c + 2][r] = a0.z;  As[c + 3][r] = a0.w;
      As[c + 16][r] = a1.x; As[c + 17][r] = a1.y; As[c + 18][r] = a1.z; As[c + 19][r] = a1.w;
    }
    {
      const int r = tid >> 4;           // 0..15
      const int c = (tid & 15) << 2;    // 0..60
      *reinterpret_cast<float4*>(&Bs[r][c]) =
          *reinterpret_cast<const float4*>(&W[(size_t)(k0 + r) * N + bn + c]);
      *reinterpret_cast<float4*>(&Bs[r + 16][c]) =
          *reinterpret_cast<const float4*>(&W[(size_t)(k0 + 16 + r) * N + bn + c]);
    }
    __syncthreads();
#pragma unroll
    for (int kk = 0; kk < 32; ++kk) {
      const float4 av = *reinterpret_cast<const float4*>(&As[kk][ty * 4]);  // 16-lane broadcast
      const float4 bv = *reinterpret_cast<const float4*>(&Bs[kk][tx * 4]);  // 2-way, free
      acc[0][0] = fmaf(av.x, bv.x, acc[0][0]); acc[0][1] = fmaf(av.x, bv.y, acc[0][1]);
      acc[0][2] = fmaf(av.x, bv.z, acc[0][2]); acc[0][3] = fmaf(av.x, bv.w, acc[0][3]);
      acc[1][0] = fmaf(av.y, bv.x, acc[1][0]); acc[1][1] = fmaf(av.y, bv.y, acc[1][1]);
      acc[1][2] = fmaf(av.y, bv.z, acc[1][2]); acc[1][3] = fmaf(av.y, bv.w, acc[1][3]);
      acc[2][0] = fmaf(av.z, bv.x, acc[2][0]); acc[2][1] = fmaf(av.z, bv.y, acc[2][1]);
      acc[2][2] = fmaf(av.z, bv.z, acc[2][2]); acc[2][3] = fmaf(av.z, bv.w, acc[2][3]);
      acc[3][0] = fmaf(av.w, bv.x, acc[3][0]); acc[3][1] = fmaf(av.w, bv.y, acc[3][1]);
      acc[3][2] = fmaf(av.w, bv.z, acc[3][2]); acc[3][3] = fmaf(av.w, bv.w, acc[3][3]);
    }
    __syncthreads();
  }
#pragma unroll
  for (int i = 0; i < 4; ++i) {
    const int row = bm + ty * 4 + i;
#pragma unroll
    for (int j = 0; j < 4; ++j) {
      const int col = bn + tx * 4 + j;
      C[(size_t)row * N + col] = acc[i][j] + bias[col];
    }
  }
}

// Same GEMM but writes C TRANSPOSED: Ct[N][M].
__global__ __launch_bounds__(256) void gemm_bias_kernelT(
    const float* __restrict__ A, const float* __restrict__ W,
    const float* __restrict__ bias, float* __restrict__ Ct,
    int M, int N, int K)
{
  __shared__ float As[32][68];
  __shared__ float Bs[32][68];
  const int bm = blockIdx.y * 64;
  const int bn = blockIdx.x * 64;
  const int tid = threadIdx.x;
  const int tx = tid & 15, ty = tid >> 4;
  float acc[4][4] = {};
  for (int k0 = 0; k0 < K; k0 += 32) {
    {
      const int r = tid >> 2;
      const int c = (tid & 3) << 2;
      const float4 a0 = *reinterpret_cast<const float4*>(&A[(size_t)(bm + r) * K + k0 + c]);
      const float4 a1 = *reinterpret_cast<const float4*>(&A[(size_t)(bm + r) * K + k0 + 16 + c]);
      As[c + 0][r] = a0.x;  As[c + 1][r] = a0.y;  As[c + 2][r] = a0.z;  As[c + 3][r] = a0.w;
      As[c + 16][r] = a1.x; As[c + 17][r] = a1.y; As[c + 18][r] = a1.z; As[c + 19][r] = a1.w;
    }
    {
      const int r = tid >> 4;
      const int c = (tid & 15) << 2;
      *reinterpret_cast<float4*>(&Bs[r][c]) =
          *reinterpret_cast<const float4*>(&W[(size_t)(k0 + r) * N + bn + c]);
      *reinterpret_cast<float4*>(&Bs[r + 16][c]) =
          *reinterpret_cast<const float4*>(&W[(size_t)(k0 + 16 + r) * N + bn + c]);
    }
    __syncthreads();
#pragma unroll
    for (int kk = 0; kk < 32; ++kk) {
      const float4 av = *reinterpret_cast<const float4*>(&As[kk][ty * 4]);
      const float4 bv = *reinterpret_cast<const float4*>(&Bs[kk][tx * 4]);
      acc[0][0] = fmaf(av.x, bv.x, acc[0][0]); acc[0][1] = fmaf(av.x, bv.y, acc[0][1]);
      acc[0][2] = fmaf(av.x, bv.z, acc[0][2]); acc[0][3] = fmaf(av.x, bv.w, acc[0][3]);
      acc[1][0] = fmaf(av.y, bv.x, acc[1][0]); acc[1][1] = fmaf(av.y, bv.y, acc[1][1]);
      acc[1][2] = fmaf(av.y, bv.z, acc[1][2]); acc[1][3] = fmaf(av.y, bv.w, acc[1][3]);
      acc[2][0] = fmaf(av.z, bv.x, acc[2][0]); acc[2][1] = fmaf(av.z, bv.y, acc[2][1]);
      acc[2][2] = fmaf(av.z, bv.z, acc[2][2]); acc[2][3] = fmaf(av.z, bv.w, acc[2][3]);
      acc[3][0] = fmaf(av.w, bv.x, acc[3][0]); acc[3][1] = fmaf(av.w, bv.y, acc[3][1]);
      acc[3][2] = fmaf(av.w, bv.z, acc[3][2]); acc[3][3] = fmaf(av.w, bv.w, acc[3][3]);
    }
    __syncthreads();
  }
#pragma unroll
  for (int j = 0; j < 4; ++j) {
    const int col = bn + tx * 4 + j;
    const float bb = bias[col];
    const float4 v = make_float4(acc[0][j] + bb, acc[1][j] + bb, acc[2][j] + bb, acc[3][j] + bb);
    *reinterpret_cast<float4*>(&Ct[(size_t)col * M + bm + ty * 4]) = v;
  }
}

// ---------------- V_combined = mean over heads of V ----------------
__global__ __launch_bounds__(256) void vcombine_kernel(const float* __restrict__ V,
                                                       float* __restrict__ Vc)
{
  const int idx = blockIdx.x * 256 + threadIdx.x;
  if (idx >= M_ * DK_) return;
  const int row = idx >> 6, d = idx & 63;
  float s = 0.f;
#pragma unroll
  for (int h = 0; h < H_; ++h) s += V[(size_t)row * D_ + h * DK_ + d];
  Vc[idx] = s * 0.125f;
}

// ---------------- fused causal scores + 1.5-entmax (8 rows / 8 waves / block) ----------------
// Q is read via block-uniform SCALAR loads (s_load) inside the score loop — no LDS
// staging, no q ds_read_b128 broadcast traffic (was ~128 b128/thread/head).
// Score branch is wave-uniform; partially-active lanes clamp s0 (duplicate, identical writes).
__global__ __launch_bounds__(512, 4)
void attn_kernel(
    const float* __restrict__ Qg, const float* __restrict__ Kt,
    const float* __restrict__ Vc, float* __restrict__ wavg,
    float* __restrict__ attn_out)
{
  __shared__ float sc[TQ_][T_];         // 64 KB: scores; reused as wsum at end
  __shared__ float part[4][TQ_][DK_];   // 8 KB: PV partials

  const int tid = threadIdx.x;
  const int b = blockIdx.x & 1;
  const int tile = (NTL_ - 1) - (blockIdx.x >> 1);  // heavy tiles first
  const int t0 = tile * TQ_;
  const int nS = t0 + TQ_;              // needed s range [0, nS)
  const int wave = __builtin_amdgcn_readfirstlane(tid >> 6);  // 0..7 (SGPR)
  const int lane = tid & 63;
  const int n = t0 + wave + 1;          // support size for this wave's row (SGPR)
  float* const scw = &sc[wave][0];

  float wacc[32];
#pragma unroll
  for (int j = 0; j < 32; ++j) wacc[j] = 0.f;

  for (int h = 0; h < H_; ++h) {
    // ---- scores: z[r][s] = (Q[t0+r].K[s]) * 0.0625 ----
    if (wave * 256 < nS) {              // wave-uniform (scalar) guard
      const int s0 = min(tid * 4, nS - 4);   // clamp: duplicates write identical values
      const float* Ktp = &Kt[(size_t)(h * DK_) * M_ + b * T_ + s0];
      const float* Qp  = &Qg[(size_t)(b * T_ + t0) * D_ + h * DK_];  // block-uniform base
      float4 a[TQ_];
#pragma unroll
      for (int r = 0; r < TQ_; ++r) a[r] = make_float4(0.f, 0.f, 0.f, 0.f);
#pragma unroll 2
      for (int d4 = 0; d4 < 16; ++d4) {
        const float4 k0 = *reinterpret_cast<const float4*>(Ktp + (size_t)(d4 * 4 + 0) * M_);
        const float4 k1 = *reinterpret_cast<const float4*>(Ktp + (size_t)(d4 * 4 + 1) * M_);
        const float4 k2 = *reinterpret_cast<const float4*>(Ktp + (size_t)(d4 * 4 + 2) * M_);
        const float4 k3 = *reinterpret_cast<const float4*>(Ktp + (size_t)(d4 * 4 + 3) * M_);
#pragma unroll
        for (int r = 0; r < TQ_; ++r) {
          // block-uniform indices -> scalar loads (SMEM pipe), SGPR operand in FMA
          const float q0 = Qp[r * D_ + d4 * 4 + 0];
          const float q1 = Qp[r * D_ + d4 * 4 + 1];
          const float q2 = Qp[r * D_ + d4 * 4 + 2];
          const float q3 = Qp[r * D_ + d4 * 4 + 3];
          a[r].x = fmaf(q0, k0.x, a[r].x); a[r].y = fmaf(q0, k0.y, a[r].y);
          a[r].z = fmaf(q0, k0.z, a[r].z); a[r].w = fmaf(q0, k0.w, a[r].w);
          a[r].x = fmaf(q1, k1.x, a[r].x); a[r].y = fmaf(q1, k1.y, a[r].y);
          a[r].z = fmaf(q1, k1.z, a[r].z); a[r].w = fmaf(q1, k1.w, a[r].w);
          a[r].x = fmaf(q2, k2.x, a[r].x); a[r].y = fmaf(q2, k2.y, a[r].y);
          a[r].z = fmaf(q2, k2.z, a[r].z); a[r].w = fmaf(q2, k2.w, a[r].w);
          a[r].x = fmaf(q3, k3.x, a[r].x); a[r].y = fmaf(q3, k3.y, a[r].y);
          a[r].z = fmaf(q3, k3.z, a[r].z); a[r].w = fmaf(q3, k3.w, a[r].w);
        }
      }
#pragma unroll
      for (int r = 0; r < TQ_; ++r) {
        a[r].x *= 0.0625f; a[r].y *= 0.0625f; a[r].z *= 0.0625f; a[r].w *= 0.0625f;
        *reinterpret_cast<float4*>(&sc[r][s0]) = a[r];
      }
    }
    __syncthreads();

    // ---- 1.5-entmax on row t0+wave ----
    float srow[32];
#pragma unroll
    for (int j = 0; j < 32; ++j) {
      if (j * 64 < n) {                   // scalar guard (n is SGPR)
        const int s = lane + j * 64;
        const float v = scw[s];
        srow[j] = (s < n) ? v : -1e30f;
      }
    }

    float mx = -1e30f;
#pragma unroll
    for (int j = 0; j < 32; ++j)
      if (j * 64 < n) mx = fmaxf(mx, srow[j]);
#pragma unroll
    for (int m = 32; m >= 1; m >>= 1) mx = fmaxf(mx, __shfl_xor(mx, m, 64));

    // tau0 = mx-1 (f >= 0). 3 Michelot jumps (exact tau for current support),
    // then Newton; break on |f| < 1e-5.
    float tau = mx - 1.0f;
#pragma unroll 1
    for (int it = 0; it < 12; ++it) {
      float s1 = 0.f, s2 = 0.f, cn = 0.f;
#pragma unroll
      for (int j = 0; j < 32; ++j) {
        if (j * 64 < n) {
          const float u = fmaxf(srow[j] - tau, 0.f);
          s1 += u;
          s2 = fmaf(u, u, s2);
          cn += (u > 0.f) ? 1.f : 0.f;
        }
      }
#pragma unroll
      for (int m = 32; m >= 1; m >>= 1) {
        s1 += __shfl_xor(s1, m, 64);
        s2 += __shfl_xor(s2, m, 64);
      }
      if (fabsf(s2 - 1.0f) < 1e-5f) break;  // wave-uniform
      if (it < 3) {
#pragma unroll
        for (int m = 32; m >= 1; m >>= 1) cn += __shfl_xor(cn, m, 64);
        const float kf = fmaxf(cn, 1.f);
        const float mu = tau + s1 / kf;
        const float ss = s2 - s1 * s1 / kf;
        tau = mu - sqrtf(fmaxf((1.0f - ss) / kf, 0.f));
      } else {
        tau += (s2 - 1.0f) / fmaxf(2.f * s1, 1e-12f);
      }
    }
    tau = fminf(tau, mx - 1e-8f);

#pragma unroll
    for (int j = 0; j < 32; ++j) {
      if (j * 64 < n) {
        const float u = fmaxf(srow[j] - tau, 0.f);
        wacc[j] = fmaf(u, u, wacc[j]);
      }
    }
    __syncthreads();  // entmax reads done; sc free for next head's scores
  }

  // dump register weights to LDS (full row; tails are zero)
#pragma unroll
  for (int j = 0; j < 32; ++j) scw[lane + j * 64] = wacc[j];
  __syncthreads();

  // weights_avg: coalesced float4 stores, full T rows
  for (int i4 = tid; i4 < TQ_ * T_ / 4; i4 += 512) {
    const int r = i4 >> 9;                 // / (T_/4 = 512)
    const int c4 = i4 & 511;
    float4 w = reinterpret_cast<const float4*>(&sc[r][0])[c4];
    w.x *= 0.125f; w.y *= 0.125f; w.z *= 0.125f; w.w *= 0.125f;
    reinterpret_cast<float4*>(&wavg[(size_t)(b * T_ + t0 + r) * T_])[c4] = w;
  }

  // PV: wave w handles s ≡ (w&3) mod 4, rows (w>>2)*4 .. +3
  {
    const int sg = wave & 3;
    const int rb = (wave >> 2) * 4;
    float a0 = 0.f, a1 = 0.f, a2 = 0.f, a3 = 0.f;
    for (int s = sg; s < nS; s += 4) {
      const float v = Vc[(size_t)(b * T_ + s) * DK_ + lane];
      a0 += sc[rb + 0][s] * v;
      a1 += sc[rb + 1][s] * v;
      a2 += sc[rb + 2][s] * v;
      a3 += sc[rb + 3][s] * v;
    }
    part[sg][rb + 0][lane] = a0;
    part[sg][rb + 1][lane] = a1;
    part[sg][rb + 2][lane] = a2;
    part[sg][rb + 3][lane] = a3;
  }
  __syncthreads();
  {
    const int r = wave;
    const float o = (part[0][r][lane] + part[1][r][lane] +
                     part[2][r][lane] + part[3][r][lane]) * 0.125f;
    attn_out[(size_t)(b * T_ + t0 + r) * DK_ + lane] = o;
  }
}

extern "C" void kernel_launch(void* const* d_in, const int* in_sizes, int n_in,
                              void* d_out, int out_size, void* d_ws, size_t ws_size,
                              hipStream_t stream)
{
  const float* x  = (const float*)d_in[0];
  const float* Wq = (const float*)d_in[1];
  const float* bq = (const float*)d_in[2];
  const float* Wk = (const float*)d_in[3];
  const float* bk = (const float*)d_in[4];
  const float* Wv = (const float*)d_in[5];
  const float* bv = (const float*)d_in[6];
  const float* Wo = (const float*)d_in[7];
  const float* bo = (const float*)d_in[8];
  float* out = (float*)d_out;
  float* ws  = (float*)d_ws;

  float* Q  = ws;                        // [M,512]
  float* Kt = Q + (size_t)M_ * D_;       // [512,M]
  float* V  = Kt + (size_t)D_ * M_;      // [M,512]
  float* Vc = V + (size_t)M_ * D_;       // [M,64]
  float* AO = Vc + (size_t)M_ * DK_;     // [M,64]

  float* out1 = out;                    // [B,T,D]
  float* wavg = out + (size_t)M_ * D_;  // [B,T,T]

  const dim3 gp(D_ / 64, M_ / 64);  // (8, 64)
  gemm_bias_kernel <<<gp, 256, 0, stream>>>(x, Wq, bq, Q,  M_, D_, D_);
  gemm_bias_kernelT<<<gp, 256, 0, stream>>>(x, Wk, bk, Kt, M_, D_, D_);
  gemm_bias_kernel <<<gp, 256, 0, stream>>>(x, Wv, bv, V,  M_, D_, D_);
  vcombine_kernel<<<(M_ * DK_ + 255) / 256, 256, 0, stream>>>(V, Vc);
  attn_kernel<<<B_ * NTL_, 512, 0, stream>>>(Q, Kt, Vc, wavg, AO);
  gemm_bias_kernel<<<gp, 256, 0, stream>>>(AO, Wo, bo, out1, M_, D_, DK_);
}